// Round 1
// baseline (72.167 us; speedup 1.0000x reference)
//
#include <hip/hip_runtime.h>
#include <math.h>

// Tropical (max-plus) 3x3 conv:
// out[b,o,y,x] = max_{c,dy,dx} imgs[b,c,y+dy-1,x+dx-1] + kernel[o,c,2-dy,2-dx]
// B=8, C=32, O=32, H=W=32, PADDING=1 (with -inf), fp32.

constexpr int B = 8, C = 32, O = 32, H = 32, W = 32;
constexpr int LW = 40;    // LDS row width in floats; data at xx=4..35, -inf pads at xx=3 and xx=36
constexpr int ROWS = 10;  // rows y0-1 .. y0+8 for an 8-row output group

__global__ __launch_bounds__(256, 2) void trop_conv_kernel(
    const float* __restrict__ img, const float* __restrict__ kern,
    float* __restrict__ out) {
  __shared__ float simg[C][ROWS][LW];  // 32*10*40*4 = 50 KB

  const int tid = threadIdx.x;
  const int blk = blockIdx.x;
  const int rowgrp = blk & 3;            // 4 groups of 8 output rows
  const int o0 = ((blk >> 2) & 15) * 2;  // pair of output channels
  const int b = blk >> 6;
  const int y0 = rowgrp * 8 - 1;         // global row corresponding to LDS r=0

  // ---- stage 10 rows x 32 channels into LDS (padded with -inf) ----
  const float4* img4 = (const float4*)(img + b * C * H * W);
  float4* simg4 = (float4*)simg;
  // items: c(32) x r(10) x seg(10 float4 per row) = 3200 float4
  for (int i = tid; i < C * ROWS * (LW / 4); i += 256) {
    int seg = i % (LW / 4);
    int cr = i / (LW / 4);
    int r = cr % ROWS;
    int c = cr / ROWS;
    int gy = y0 + r;
    float4 v = make_float4(-INFINITY, -INFINITY, -INFINITY, -INFINITY);
    if (seg >= 1 && seg <= 8 && gy >= 0 && gy < H) {
      v = img4[(c * H + gy) * (W / 4) + (seg - 1)];  // global x = 4*(seg-1)..
    }
    simg4[i] = v;
  }
  __syncthreads();

  const int x = tid & 31;
  const int ylocal = tid >> 5;  // 0..7

  // weights for the two output channels (wave-uniform -> scalar loads)
  const float* wA = kern + (size_t)(o0 + 0) * C * 9;
  const float* wB = kern + (size_t)(o0 + 1) * C * 9;

  float a0 = -INFINITY, a1 = -INFINITY, a2 = -INFINITY;
  float b0 = -INFINITY, b1 = -INFINITY, b2 = -INFINITY;

#pragma unroll
  for (int c = 0; c < C; ++c) {
    // tap (dy,dx): LDS [c][ylocal+dy][x+3+dx]  (xx = global_x + 4, dx0 -> +3)
    const float* srow = &simg[c][ylocal][x + 3];
#pragma unroll
    for (int dy = 0; dy < 3; ++dy) {
      float v0 = srow[dy * LW + 0];
      float v1 = srow[dy * LW + 1];
      float v2 = srow[dy * LW + 2];
      // flipped weights: tap(dy,dx) <-> w[c*9 + (2-dy)*3 + (2-dx)]
      int wb = c * 9 + (2 - dy) * 3;
      float tA = fmaxf(fmaxf(v0 + wA[wb + 2], v1 + wA[wb + 1]), v2 + wA[wb + 0]);
      float tB = fmaxf(fmaxf(v0 + wB[wb + 2], v1 + wB[wb + 1]), v2 + wB[wb + 0]);
      if (dy == 0) { a0 = fmaxf(a0, tA); b0 = fmaxf(b0, tB); }
      else if (dy == 1) { a1 = fmaxf(a1, tA); b1 = fmaxf(b1, tB); }
      else { a2 = fmaxf(a2, tA); b2 = fmaxf(b2, tB); }
    }
  }

  const int y = rowgrp * 8 + ylocal;
  float* op = out + (((size_t)b * O + o0) * H + y) * W + x;
  op[0] = fmaxf(fmaxf(a0, a1), a2);
  op[H * W] = fmaxf(fmaxf(b0, b1), b2);
}

extern "C" void kernel_launch(void* const* d_in, const int* in_sizes, int n_in,
                              void* d_out, int out_size, void* d_ws, size_t ws_size,
                              hipStream_t stream) {
  const float* img = (const float*)d_in[0];
  const float* kern = (const float*)d_in[1];
  float* out = (float*)d_out;
  // grid: b(8) * o-pair(16) * rowgrp(4) = 512 blocks
  trop_conv_kernel<<<dim3(B * (O / 2) * 4), dim3(256), 0, stream>>>(img, kern, out);
}

// Round 4
// 71.973 us; speedup vs baseline: 1.0027x; 1.0027x over previous
//
#include <hip/hip_runtime.h>
#include <math.h>

// Tropical (max-plus) 3x3 conv:
// out[b,o,y,x] = max_{c,dy,dx} imgs[b,c,y+dy-1,x+dx-1] + kernel[o,c,2-dy,2-dx]
// B=8, C=32, O=32, H=W=32, PADDING=1 (-inf), fp32.
//
// R4 design (= R3 with the convergence bug fixed):
//  - lane = (x 0..31, ytile 0..3), each lane: 2 y-rows x 2 output channels
//  - img rows via coalesced global_load_dword (vmcnt domain, L2-resident)
//  - x+-1 via UNCONDITIONAL __shfl_up/__shfl_down executed by all lanes,
//    edge lanes masked to -inf AFTERWARDS with a select. R2/R3 put the
//    shuffle inside a ternary arm -> clang emits a divergent branch ->
//    x==0/31 lanes inactive during the cross-lane op -> neighbors read 0
//    (ds_bpermute/DPP return 0 for inactive source lanes) -> absmax 3.81
//    identical for both mechanisms.
//  - weights via uniform ds_read_b128 from 16-float-padded LDS (ordered lgkm)
//  - NO s_load in hot loop (R1: SMEM+DS lgkm mixing serialized to 72us)

constexpr int B = 8, C = 32, O = 32, H = 32, W = 32;

__device__ __forceinline__ float f3(float a, float b, float c) {
  return fmaxf(fmaxf(a, b), c);  // -> v_max3_f32
}

__global__ __launch_bounds__(128, 2) void trop_conv_kernel(
    const float* __restrict__ img, const float* __restrict__ kern,
    float* __restrict__ out) {
  __shared__ float sw[2 * 32 * 16];  // [po][c][16], taps 0..8 valid

  const int tid = threadIdx.x;
  const int blk = blockIdx.x;
  const int yq = blk & 3;           // quarter of rows (8 rows)
  const int op = (blk >> 2) & 15;   // o-pair index
  const int b = blk >> 6;

  // ---- stage this o-pair's 576 weights into padded LDS ----
  const float* kw = kern + op * 576;  // kern[2*op .. 2*op+2) contiguous
  for (int j = tid; j < 576; j += 128) {
    int po = j >= 288;
    int r = j - po * 288;
    int c = r / 9;
    int t = r - c * 9;
    sw[po * 512 + c * 16 + t] = kw[j];
  }
  __syncthreads();

  const int x = tid & 31;
  const int ytl = tid >> 5;             // 0..3
  const int y0 = yq * 8 + ytl * 2;      // output rows y0, y0+1

  // per-lane clamped row offsets (floats), loop-invariant
  int ro0, ro1, ro2, ro3;
  {
    int yy0 = y0 - 1; yy0 = yy0 < 0 ? 0 : yy0;
    int yy3 = y0 + 2; yy3 = yy3 > 31 ? 31 : yy3;
    ro0 = yy0 * W + x;
    ro1 = y0 * W + x;
    ro2 = (y0 + 1) * W + x;
    ro3 = yy3 * W + x;
  }
  const bool top_oob = (y0 == 0);
  const bool bot_oob = (y0 == 30);
  const bool xz = (x == 0);
  const bool xe = (x == 31);
  const float NEG = -__builtin_huge_valf();

  const float* ib = img + b * C * H * W;

  float a00 = NEG, a10 = NEG;  // o = 2*op,   rows y0 / y0+1
  float a01 = NEG, a11 = NEG;  // o = 2*op+1

#pragma unroll 8
  for (int c = 0; c < C; ++c) {
    const float* ic = ib + c * H * W;
    float v0 = ic[ro0];
    float v1 = ic[ro1];
    float v2 = ic[ro2];
    float v3 = ic[ro3];
    v0 = top_oob ? NEG : v0;
    v3 = bot_oob ? NEG : v3;

    // Cross-lane shifts: UNCONDITIONAL (all 64 lanes active — convergent op
    // must not sit inside a ternary/branch), THEN mask the edge lanes.
    float l0 = __shfl_up(v0, 1), r0 = __shfl_down(v0, 1);
    float l1 = __shfl_up(v1, 1), r1 = __shfl_down(v1, 1);
    float l2 = __shfl_up(v2, 1), r2 = __shfl_down(v2, 1);
    float l3 = __shfl_up(v3, 1), r3 = __shfl_down(v3, 1);
    l0 = xz ? NEG : l0;  r0 = xe ? NEG : r0;
    l1 = xz ? NEG : l1;  r1 = xe ? NEG : r1;
    l2 = xz ? NEG : l2;  r2 = xe ? NEG : r2;
    l3 = xz ? NEG : l3;  r3 = xe ? NEG : r3;

    // uniform (broadcast) weight reads; slots s0..s8, s = 8 - (3*dy + dx)
    const float4 A0 = *(const float4*)&sw[c * 16];
    const float4 A1 = *(const float4*)&sw[c * 16 + 4];
    const float A8 = sw[c * 16 + 8];
    const float4 B0 = *(const float4*)&sw[512 + c * 16];
    const float4 B1 = *(const float4*)&sw[512 + c * 16 + 4];
    const float B8 = sw[512 + c * 16 + 8];

    // out(y) taps rows (v_dy at y-1+dy), dx: L/C/R; weight slot 8-3dy-dx
    {  // o = 2*op, py=0 (rows v0,v1,v2)
      float t0 = f3(l0 + A8, v0 + A1.w, r0 + A1.z);
      float t1 = f3(l1 + A1.y, v1 + A1.x, r1 + A0.w);
      float t2 = f3(l2 + A0.z, v2 + A0.y, r2 + A0.x);
      a00 = fmaxf(a00, f3(t0, t1, t2));
    }
    {  // o = 2*op, py=1 (rows v1,v2,v3)
      float t0 = f3(l1 + A8, v1 + A1.w, r1 + A1.z);
      float t1 = f3(l2 + A1.y, v2 + A1.x, r2 + A0.w);
      float t2 = f3(l3 + A0.z, v3 + A0.y, r3 + A0.x);
      a10 = fmaxf(a10, f3(t0, t1, t2));
    }
    {  // o = 2*op+1, py=0
      float t0 = f3(l0 + B8, v0 + B1.w, r0 + B1.z);
      float t1 = f3(l1 + B1.y, v1 + B1.x, r1 + B0.w);
      float t2 = f3(l2 + B0.z, v2 + B0.y, r2 + B0.x);
      a01 = fmaxf(a01, f3(t0, t1, t2));
    }
    {  // o = 2*op+1, py=1
      float t0 = f3(l1 + B8, v1 + B1.w, r1 + B1.z);
      float t1 = f3(l2 + B1.y, v2 + B1.x, r2 + B0.w);
      float t2 = f3(l3 + B0.z, v3 + B0.y, r3 + B0.x);
      a11 = fmaxf(a11, f3(t0, t1, t2));
    }
  }

  const int o0 = op * 2;
  out[((b * O + o0) * H + y0) * W + x] = a00;
  out[((b * O + o0) * H + y0 + 1) * W + x] = a10;
  out[((b * O + o0 + 1) * H + y0) * W + x] = a01;
  out[((b * O + o0 + 1) * H + y0 + 1) * W + x] = a11;
}

extern "C" void kernel_launch(void* const* d_in, const int* in_sizes, int n_in,
                              void* d_out, int out_size, void* d_ws, size_t ws_size,
                              hipStream_t stream) {
  const float* img = (const float*)d_in[0];
  const float* kern = (const float*)d_in[1];
  float* out = (float*)d_out;
  // grid: b(8) x o-pair(16) x y-quarter(4) = 512 blocks of 128 threads
  trop_conv_kernel<<<dim3(512), dim3(128), 0, stream>>>(img, kern, out);
}